// Round 6
// baseline (849.299 us; speedup 1.0000x reference)
//
#include <hip/hip_runtime.h>
#include <hip/hip_bf16.h>

// Problem dims (fixed)
#define BB 256   // batch
#define SS 128   // seq len
#define EE 512   // embed dim
#define HH 1024  // hidden
#define VV 128   // vocab
#define CC 18    // classes

typedef _Float16 f16x8 __attribute__((ext_vector_type(8)));
typedef _Float16 f16x4 __attribute__((ext_vector_type(4)));
typedef float    f32x4 __attribute__((ext_vector_type(4)));

// ws layout (bytes)
//  0x000000: _Float16 hbuf[2][2][256][1024]   (2 MB) [buf][hi/lo][b][k]; zeroed (tag=0)
//  0x210000: float emb_proj[128][1024]        (512 KB) = emb@W_ih^T + b_ih + b_hh
//  0x290000: float last[256][1024]            (1 MB)  gathered final hidden
//  0x390000: float z[256][1024]               (1 MB)  relu(last@W1^T + b1)
#define HBUF_OFF  0x000000
#define EP_OFF    0x210000
#define LAST_OFF  0x290000
#define Z_OFF     0x390000

__device__ inline f16x8 cvt8(f32x4 a, f32x4 b) {
  f16x8 r;
  r[0] = (_Float16)a.x; r[1] = (_Float16)a.y; r[2] = (_Float16)a.z; r[3] = (_Float16)a.w;
  r[4] = (_Float16)b.x; r[5] = (_Float16)b.y; r[6] = (_Float16)b.z; r[7] = (_Float16)b.w;
  return r;
}

// Coherence-point (MALL) access: relaxed agent-scope atomics compile to
// global_load/store with sc1 => bypass the non-coherent per-XCD L2.
__device__ inline f16x8 ld_cp16(const _Float16* p) {
  const unsigned long long* q = (const unsigned long long*)p;
  union { unsigned long long u[2]; f16x8 v; } r;
  r.u[0] = __hip_atomic_load(q + 0, __ATOMIC_RELAXED, __HIP_MEMORY_SCOPE_AGENT);
  r.u[1] = __hip_atomic_load(q + 1, __ATOMIC_RELAXED, __HIP_MEMORY_SCOPE_AGENT);
  return r.v;
}

// Self-timed h granule: 4 cols packed in one 8B word per plane; 2 mantissa LSBs
// of element 3 carry the step tag (t&3). The lo plane is computed from the
// TAGGED hi, so the hi tag perturbation is absorbed exactly; only lo3's own
// stolen bits remain (~2^-20 relative). Each 8B store is single-copy atomic,
// so any torn/stale word shows a wrong tag -> consumer retries.
__device__ inline void pack_store(_Float16* dhi, _Float16* dlo, const float th[4], int tg) {
  union { unsigned short us[4]; unsigned long long u; } H, L;
#pragma unroll
  for (int i = 0; i < 4; ++i) {
    union { _Float16 f; unsigned short b; } hc; hc.f = (_Float16)th[i];
    unsigned short hb = hc.b;
    if (i == 3) hb = (unsigned short)((hb & 0xFFFCu) | (unsigned)tg);
    H.us[i] = hb;
    union { unsigned short b; _Float16 f; } hd; hd.b = hb;
    const float lv = (th[i] - (float)hd.f) * 4096.0f;
    union { _Float16 f; unsigned short b; } lc; lc.f = (_Float16)lv;
    unsigned short lb = lc.b;
    if (i == 3) lb = (unsigned short)((lb & 0xFFFCu) | (unsigned)tg);
    L.us[i] = lb;
  }
  __hip_atomic_store((unsigned long long*)dhi, H.u, __ATOMIC_RELAXED, __HIP_MEMORY_SCOPE_AGENT);
  __hip_atomic_store((unsigned long long*)dlo, L.u, __ATOMIC_RELAXED, __HIP_MEMORY_SCOPE_AGENT);
}

// tag mismatch detector: elements 3 and 7 of a loaded f16x8 carry tags
__device__ inline int tag_bad(f16x8 v, unsigned tg) {
  union { f16x8 f; unsigned u[4]; } c; c.f = v;
  return (int)((((c.u[1] >> 16) ^ tg) | ((c.u[3] >> 16) ^ tg)) & 3u);
}

__device__ inline float tanh_fast(float x) {
  const float e = __expf(-2.0f * fabsf(x));
  return copysignf((1.0f - e) / (1.0f + e), x);
}

// ---------------- K1: emb_proj[v][h] = sum_e emb[v][e]*W_ih[h][e] + b_ih[h] + b_hh[h]
__global__ __launch_bounds__(256) void k_embproj(const float* __restrict__ emb,
                                                 const float* __restrict__ W_ih,
                                                 const float* __restrict__ b_ih,
                                                 const float* __restrict__ b_hh,
                                                 float* __restrict__ ep) {
  __shared__ float red[4][16][66];
  const int bid = blockIdx.x;
  const int v0 = (bid & 7) * 16;
  const int h0 = (bid >> 3) * 64;
  const int tid = threadIdx.x;
  const int w = tid >> 6, lane = tid & 63, lr = lane & 15, lk = lane >> 4;

  f32x4 acc[4] = {};
  const int vrow = v0 + lr;
#pragma unroll
  for (int ki = 0; ki < 4; ++ki) {
    const int k = w * 128 + ki * 32 + lk * 8;
    const f32x4* pa = (const f32x4*)(emb + vrow * EE + k);
    f16x8 af = cvt8(pa[0], pa[1]);
#pragma unroll
    for (int nt = 0; nt < 4; ++nt) {
      const int hcol = h0 + nt * 16 + lr;
      const f32x4* pb = (const f32x4*)(W_ih + hcol * EE + k);
      f16x8 bf = cvt8(pb[0], pb[1]);
      acc[nt] = __builtin_amdgcn_mfma_f32_16x16x32_f16(af, bf, acc[nt], 0, 0, 0);
    }
  }
#pragma unroll
  for (int nt = 0; nt < 4; ++nt)
#pragma unroll
    for (int j = 0; j < 4; ++j)
      red[w][lk * 4 + j][nt * 16 + lr] = acc[nt][j];
  __syncthreads();

  const int r = tid >> 4, cg = tid & 15, cc0 = cg * 4;
  const int vvr = v0 + r;
#pragma unroll
  for (int i = 0; i < 4; ++i) {
    const int hcol = h0 + cc0 + i;
    float s = red[0][r][cc0 + i] + red[1][r][cc0 + i] +
              red[2][r][cc0 + i] + red[3][r][cc0 + i];
    ep[vvr * HH + hcol] = s + b_ih[hcol] + b_hh[hcol];
  }
}

// ---------------- K2: persistent RNN scan, SELF-TIMED h exchange.
// 256 blocks = 16 groups (16 batch rows) x 16 col-blocks (64 cols). No flags, no
// group barrier: every 8B h-word carries a 2-bit step tag; producers fire-and-
// forget sc1 stores; consumers poll-load until all their words carry this step's
// tag. Serialized MALL round-trips per step: ~2 (was 4 with the flag barrier).
// W_hh register-resident f16; h = f16 hi + 4096*lo planes, double-buffered.
__global__ __launch_bounds__(256, 1) void k_rnn(const float* __restrict__ W_hh,
                                                const int* __restrict__ x_in,
                                                const int* __restrict__ x_len,
                                                const float* __restrict__ ep,
                                                _Float16* __restrict__ hbuf,
                                                float* __restrict__ lastb) {
  __shared__ float red[2][4][16][68];   // double-buffered: 1 syncthreads/step
  __shared__ int xin[16][128];
  __shared__ int len1[16];

  const int bid = blockIdx.x;
  const int g = bid & 15;        // group id
  const int c = bid >> 4;        // col-block
  const int row0 = g * 16, col0 = c * 64;
  const int tid = threadIdx.x;
  const int w = tid >> 6, lane = tid & 63, lr = lane & 15, lk = lane >> 4;

  for (int i = tid; i < 16 * SS; i += 256) {
    const int r_ = i >> 7, s_ = i & 127;
    xin[r_][s_] = x_in[(row0 + r_) * SS + s_];
  }
  if (tid < 16) len1[tid] = x_len[row0 + tid] - 1;

  // Register-resident W_hh fragments: wave w owns k-quarter [256w, 256w+256)
  f16x8 wreg[4][8];
#pragma unroll
  for (int nt = 0; nt < 4; ++nt) {
    const int col = col0 + nt * 16 + lr;
#pragma unroll
    for (int ki = 0; ki < 8; ++ki) {
      const int k = w * 256 + ki * 32 + lk * 8;
      const f32x4* pw = (const f32x4*)(W_hh + col * HH + k);
      wreg[nt][ki] = cvt8(pw[0], pw[1]);
    }
  }
  __syncthreads();

  int gmax = 0;
#pragma unroll
  for (int r16 = 0; r16 < 16; ++r16) gmax = max(gmax, len1[r16]);

  const int arow = row0 + lr;
  const int r = tid >> 4, cc0 = (tid & 15) * 4;
  const int grow = row0 + r;

  // ---- t = 0: h0 == 0, so h1 = tanh(pre_0). No loads, no MFMA, no sync.
  {
    const int vv = xin[r][0];
    const f32x4 pre4 = *(const f32x4*)(ep + vv * HH + col0 + cc0);
    float th[4];
    th[0] = tanh_fast(pre4.x); th[1] = tanh_fast(pre4.y);
    th[2] = tanh_fast(pre4.z); th[3] = tanh_fast(pre4.w);

    if (len1[r] == 0) {
      f32x4 o; o.x = th[0]; o.y = th[1]; o.z = th[2]; o.w = th[3];
      *(f32x4*)(lastb + (size_t)grow * HH + col0 + cc0) = o;
    }
    if (gmax >= 1)   // h1 granules, tag = 1
      pack_store(hbuf + ((size_t)(1 * 2 + 0) * BB + grow) * HH + col0 + cc0,
                 hbuf + ((size_t)(1 * 2 + 1) * BB + grow) * HH + col0 + cc0, th, 1);
  }

  for (int t = 1; t <= gmax; ++t) {
    const int bufR = t & 1;
    const unsigned tg = (unsigned)(t & 3);
    const _Float16* hr_hi = hbuf + ((size_t)(bufR * 2 + 0) * BB + arow) * HH;
    const _Float16* hr_lo = hbuf + ((size_t)(bufR * 2 + 1) * BB + arow) * HH;

    // this step's ep gather: issue early, independent of h
    const int vv = xin[r][t];
    const f32x4 pre4 = *(const f32x4*)(ep + vv * HH + col0 + cc0);

    // ---- sentinel poll (8B/lane): lanes jointly cover all 4 producers of this
    // wave's k-quarter x all 16 rows. Cheap spin until data is ~ready.
    {
      const _Float16* sp = hbuf + ((size_t)(bufR * 2 + 0) * BB + row0 + (lane & 15)) * HH
                           + (w * 4 + (lane >> 4)) * 64;
      for (;;) {
        unsigned long long s = __hip_atomic_load((const unsigned long long*)sp,
                                 __ATOMIC_RELAXED, __HIP_MEMORY_SCOPE_AGENT);
        if (__all((((int)(s >> 48)) & 3) == (int)tg)) break;
        __builtin_amdgcn_s_sleep(1);
      }
    }

    // ---- full tag-checked load round (retry on any stale/torn word)
    f16x8 ahi[8], alo[8];
    for (;;) {
#pragma unroll
      for (int ki = 0; ki < 8; ++ki) {
        const int k = w * 256 + ki * 32 + lk * 8;
        ahi[ki] = ld_cp16(hr_hi + k);
        alo[ki] = ld_cp16(hr_lo + k);
      }
      int bad = 0;
#pragma unroll
      for (int ki = 0; ki < 8; ++ki)
        bad |= tag_bad(ahi[ki], tg) | tag_bad(alo[ki], tg);
      if (!__any(bad)) break;
      __builtin_amdgcn_s_sleep(1);
    }

    // ---- MFMA (tag bits in hi are compensated by lo: h = hi + lo/4096)
    f32x4 acch[4] = {};
    f32x4 accl[4] = {};
#pragma unroll
    for (int ki = 0; ki < 8; ++ki) {
#pragma unroll
      for (int nt = 0; nt < 4; ++nt) {
        acch[nt] = __builtin_amdgcn_mfma_f32_16x16x32_f16(ahi[ki], wreg[nt][ki], acch[nt], 0, 0, 0);
        accl[nt] = __builtin_amdgcn_mfma_f32_16x16x32_f16(alo[ki], wreg[nt][ki], accl[nt], 0, 0, 0);
      }
    }
    const int p = t & 1;
#pragma unroll
    for (int nt = 0; nt < 4; ++nt)
#pragma unroll
      for (int j = 0; j < 4; ++j)
        red[p][w][lk * 4 + j][nt * 16 + lr] = acch[nt][j] + accl[nt][j] * (1.0f / 4096.0f);
    __syncthreads();   // the ONLY barrier per step (red visibility)

    // ---- cross-wave reduce + tanh
    const f32x4 s0 = *(const f32x4*)&red[p][0][r][cc0];
    const f32x4 s1 = *(const f32x4*)&red[p][1][r][cc0];
    const f32x4 s2 = *(const f32x4*)&red[p][2][r][cc0];
    const f32x4 s3 = *(const f32x4*)&red[p][3][r][cc0];
    const f32x4 sv = (s0 + s1) + (s2 + s3);

    float th[4];
    th[0] = tanh_fast(sv.x + pre4.x);
    th[1] = tanh_fast(sv.y + pre4.y);
    th[2] = tanh_fast(sv.z + pre4.z);
    th[3] = tanh_fast(sv.w + pre4.w);

    if (len1[r] == t) {
      f32x4 o; o.x = th[0]; o.y = th[1]; o.z = th[2]; o.w = th[3];
      *(f32x4*)(lastb + (size_t)grow * HH + col0 + cc0) = o;
    }

    if (t < gmax) {  // h_{t+1} granules, tag = (t+1)&3; fire-and-forget
      const int bufW = bufR ^ 1;
      pack_store(hbuf + ((size_t)(bufW * 2 + 0) * BB + grow) * HH + col0 + cc0,
                 hbuf + ((size_t)(bufW * 2 + 1) * BB + grow) * HH + col0 + cc0,
                 th, (int)((t + 1) & 3));
    }
  }
}

// ---------------- K3: z = relu(last @ W1^T + b1).
__global__ __launch_bounds__(256) void k_mlp1(const float* __restrict__ lastb,
                                              const float* __restrict__ W1,
                                              const float* __restrict__ b1,
                                              float* __restrict__ z) {
  __shared__ float red[4][16][66];
  const int bid = blockIdx.x;
  const int row0 = (bid & 15) * 16, col0 = (bid >> 4) * 64;
  const int tid = threadIdx.x;
  const int w = tid >> 6, lane = tid & 63, lr = lane & 15, lk = lane >> 4;
  const int arow = row0 + lr;

  f32x4 acch[4] = {};
  f32x4 accl[4] = {};
#pragma unroll
  for (int ki = 0; ki < 8; ++ki) {
    const int k = w * 256 + ki * 32 + lk * 8;
    const f32x4* pa = (const f32x4*)(lastb + (size_t)arow * HH + k);
    f32x4 a0 = pa[0], a1 = pa[1];
    f16x8 ahi, alo;
#pragma unroll
    for (int i = 0; i < 4; ++i) {
      float v0 = (i == 0) ? a0.x : (i == 1) ? a0.y : (i == 2) ? a0.z : a0.w;
      float v1 = (i == 0) ? a1.x : (i == 1) ? a1.y : (i == 2) ? a1.z : a1.w;
      _Float16 h0 = (_Float16)v0, h1 = (_Float16)v1;
      ahi[i] = h0; ahi[i + 4] = h1;
      alo[i] = (_Float16)((v0 - (float)h0) * 4096.0f);
      alo[i + 4] = (_Float16)((v1 - (float)h1) * 4096.0f);
    }
#pragma unroll
    for (int nt = 0; nt < 4; ++nt) {
      const int colw = col0 + nt * 16 + lr;
      const f32x4* pb = (const f32x4*)(W1 + (size_t)colw * HH + k);
      f16x8 bf = cvt8(pb[0], pb[1]);
      acch[nt] = __builtin_amdgcn_mfma_f32_16x16x32_f16(ahi, bf, acch[nt], 0, 0, 0);
      accl[nt] = __builtin_amdgcn_mfma_f32_16x16x32_f16(alo, bf, accl[nt], 0, 0, 0);
    }
  }
#pragma unroll
  for (int nt = 0; nt < 4; ++nt)
#pragma unroll
    for (int j = 0; j < 4; ++j)
      red[w][lk * 4 + j][nt * 16 + lr] = acch[nt][j] + accl[nt][j] * (1.0f / 4096.0f);
  __syncthreads();

  const int r = tid >> 4, cc0 = (tid & 15) * 4;
  const int grow = row0 + r;
#pragma unroll
  for (int i = 0; i < 4; ++i) {
    const int col = col0 + cc0 + i;
    float s = red[0][r][cc0 + i] + red[1][r][cc0 + i] +
              red[2][r][cc0 + i] + red[3][r][cc0 + i] + b1[col];
    z[(size_t)grow * HH + col] = fmaxf(s, 0.0f);
  }
}

// ---------------- K4: y = z @ W2^T + b2. One block per batch row, fp32 wave reduce.
__global__ __launch_bounds__(256) void k_mlp2(const float* __restrict__ z,
                                              const float* __restrict__ W2,
                                              const float* __restrict__ b2,
                                              float* __restrict__ out) {
  __shared__ float redy[4][CC];
  const int b = blockIdx.x;
  const int tid = threadIdx.x;
  const int w = tid >> 6, lane = tid & 63;
  const int k = w * 256 + lane * 4;

  const f32x4 z4 = *(const f32x4*)(z + (size_t)b * HH + k);
  float part[CC];
#pragma unroll
  for (int c = 0; c < CC; ++c) {
    const f32x4 w4 = *(const f32x4*)(W2 + (size_t)c * HH + k);
    part[c] = z4.x * w4.x + z4.y * w4.y + z4.z * w4.z + z4.w * w4.w;
  }
#pragma unroll
  for (int c = 0; c < CC; ++c) {
    float v = part[c];
    for (int off = 32; off; off >>= 1) v += __shfl_down(v, off, 64);
    if (lane == 0) redy[w][c] = v;
  }
  __syncthreads();
  if (tid < CC)
    out[b * CC + tid] = redy[0][tid] + redy[1][tid] + redy[2][tid] + redy[3][tid] + b2[tid];
}

extern "C" void kernel_launch(void* const* d_in, const int* in_sizes, int n_in,
                              void* d_out, int out_size, void* d_ws, size_t ws_size,
                              hipStream_t stream) {
  const int*   x_in  = (const int*)d_in[0];
  const int*   x_len = (const int*)d_in[1];
  const float* emb   = (const float*)d_in[2];
  const float* W_ih  = (const float*)d_in[3];
  const float* b_ih  = (const float*)d_in[4];
  const float* W_hh  = (const float*)d_in[5];
  const float* b_hh  = (const float*)d_in[6];
  const float* W1    = (const float*)d_in[7];
  const float* b1    = (const float*)d_in[8];
  const float* W2    = (const float*)d_in[9];
  const float* b2    = (const float*)d_in[10];

  char* ws = (char*)d_ws;
  _Float16* hbuf = (_Float16*)(ws + HBUF_OFF);
  float* ep      = (float*)(ws + EP_OFF);
  float* lastb   = (float*)(ws + LAST_OFF);
  float* z       = (float*)(ws + Z_OFF);

  // zero hbuf: tag bits become 0, never matching the first expected tags
  // (t=1 -> tag 1, t=2 -> tag 2, t=3 -> tag 3; by t=4 every granule has been
  //  overwritten with real tagged data, and staleness is caught mod 4)
  (void)hipMemsetAsync(hbuf, 0, 0x200000, stream);

  hipLaunchKernelGGL(k_embproj, dim3(128), dim3(256), 0, stream, emb, W_ih, b_ih, b_hh, ep);
  hipLaunchKernelGGL(k_rnn,    dim3(256), dim3(256), 0, stream, W_hh, x_in, x_len, ep, hbuf, lastb);
  hipLaunchKernelGGL(k_mlp1,   dim3(256), dim3(256), 0, stream, lastb, W1, b1, z);
  hipLaunchKernelGGL(k_mlp2,   dim3(256), dim3(256), 0, stream, z, W2, b2, (float*)d_out);
}

// Round 7
// 765.587 us; speedup vs baseline: 1.1093x; 1.1093x over previous
//
#include <hip/hip_runtime.h>
#include <hip/hip_bf16.h>

// Problem dims (fixed)
#define BB 256   // batch
#define SS 128   // seq len
#define EE 512   // embed dim
#define HH 1024  // hidden
#define VV 128   // vocab
#define CC 18    // classes

typedef _Float16 f16x8 __attribute__((ext_vector_type(8)));
typedef _Float16 f16x4 __attribute__((ext_vector_type(4)));
typedef float    f32x4 __attribute__((ext_vector_type(4)));

// ws layout (bytes)
//  0x000000: _Float16 hbuf[2][2][256][1024]   (2 MB) [buf][hi/lo][b][k]; written before read
//  0x200000: int flags[16][128]               (8 KB) per-(group,step) arrival counters
//  0x210000: float emb_proj[128][1024]        (512 KB) = emb@W_ih^T + b_ih + b_hh
//  0x290000: float last[256][1024]            (1 MB)  gathered final hidden
//  0x390000: float z[256][1024]               (1 MB)  relu(last@W1^T + b1)
#define HBUF_OFF  0x000000
#define FLAGS_OFF 0x200000
#define EP_OFF    0x210000
#define LAST_OFF  0x290000
#define Z_OFF     0x390000

#define WPAD 1032   // padded f16 row stride for the LDS W slice (bank spread)

__device__ inline f16x8 cvt8(f32x4 a, f32x4 b) {
  f16x8 r;
  r[0] = (_Float16)a.x; r[1] = (_Float16)a.y; r[2] = (_Float16)a.z; r[3] = (_Float16)a.w;
  r[4] = (_Float16)b.x; r[5] = (_Float16)b.y; r[6] = (_Float16)b.z; r[7] = (_Float16)b.w;
  return r;
}

// Coherence-point (MALL) access: relaxed agent-scope atomics compile to
// global_load/store with sc1 => bypass the non-coherent per-XCD L2.
__device__ inline f16x8 ld_cp16(const _Float16* p) {
  const unsigned long long* q = (const unsigned long long*)p;
  union { unsigned long long u[2]; f16x8 v; } r;
  r.u[0] = __hip_atomic_load(q + 0, __ATOMIC_RELAXED, __HIP_MEMORY_SCOPE_AGENT);
  r.u[1] = __hip_atomic_load(q + 1, __ATOMIC_RELAXED, __HIP_MEMORY_SCOPE_AGENT);
  return r.v;
}
__device__ inline void st_cp8(_Float16* p, f16x4 v) {
  union { f16x4 v; unsigned long long u; } c; c.v = v;
  __hip_atomic_store((unsigned long long*)p, c.u, __ATOMIC_RELAXED,
                     __HIP_MEMORY_SCOPE_AGENT);
}

__device__ inline float tanh_fast(float x) {
  const float e = __expf(-2.0f * fabsf(x));
  return copysignf((1.0f - e) / (1.0f + e), x);
}

// ---------------- K1: emb_proj[v][h] = sum_e emb[v][e]*W_ih[h][e] + b_ih[h] + b_hh[h]
__global__ __launch_bounds__(256) void k_embproj(const float* __restrict__ emb,
                                                 const float* __restrict__ W_ih,
                                                 const float* __restrict__ b_ih,
                                                 const float* __restrict__ b_hh,
                                                 float* __restrict__ ep) {
  __shared__ float red[4][16][66];
  const int bid = blockIdx.x;
  const int v0 = (bid & 7) * 16;
  const int h0 = (bid >> 3) * 64;
  const int tid = threadIdx.x;
  const int w = tid >> 6, lane = tid & 63, lr = lane & 15, lk = lane >> 4;

  f32x4 acc[4] = {};
  const int vrow = v0 + lr;
#pragma unroll
  for (int ki = 0; ki < 4; ++ki) {
    const int k = w * 128 + ki * 32 + lk * 8;
    const f32x4* pa = (const f32x4*)(emb + vrow * EE + k);
    f16x8 af = cvt8(pa[0], pa[1]);
#pragma unroll
    for (int nt = 0; nt < 4; ++nt) {
      const int hcol = h0 + nt * 16 + lr;
      const f32x4* pb = (const f32x4*)(W_ih + hcol * EE + k);
      f16x8 bf = cvt8(pb[0], pb[1]);
      acc[nt] = __builtin_amdgcn_mfma_f32_16x16x32_f16(af, bf, acc[nt], 0, 0, 0);
    }
  }
#pragma unroll
  for (int nt = 0; nt < 4; ++nt)
#pragma unroll
    for (int j = 0; j < 4; ++j)
      red[w][lk * 4 + j][nt * 16 + lr] = acc[nt][j];
  __syncthreads();

  const int r = tid >> 4, cg = tid & 15, cc0 = cg * 4;
  const int vvr = v0 + r;
#pragma unroll
  for (int i = 0; i < 4; ++i) {
    const int hcol = h0 + cc0 + i;
    float s = red[0][r][cc0 + i] + red[1][r][cc0 + i] +
              red[2][r][cc0 + i] + red[3][r][cc0 + i];
    ep[vvr * HH + hcol] = s + b_ih[hcol] + b_hh[hcol];
  }
}

// ---------------- K2: persistent RNN scan, W slice in LDS.
// 256 blocks = 16 groups (16 batch rows) x 16 col-blocks (64 cols). Group-local
// 16-block counting barrier per step (r4 protocol); h exchange via MALL (sc1).
// W_hh slice lives in LDS as f16 [64][1032] (padded rows -> conflict-free
// ds_read_b128 fragments). LDS residency is guaranteed - the compiler cannot
// rematerialize/spill it the way it silently did with the "register-resident"
// wreg of rounds 3-6 (VGPR_Count 148 proved wreg never actually lived in regs,
// and re-streaming W from MALL was the measured ~5.5us/step floor).
// h state: f16 hi + 4096*lo planes, double-buffered.
__global__ __launch_bounds__(256, 1) void k_rnn(const float* __restrict__ W_hh,
                                                const int* __restrict__ x_in,
                                                const int* __restrict__ x_len,
                                                const float* __restrict__ ep,
                                                _Float16* __restrict__ hbuf,
                                                int* __restrict__ flags,
                                                float* __restrict__ lastb) {
  __shared__ _Float16 wlds[64 * WPAD];   // 129 KiB
  __shared__ float red[4][16][68];       // 17 KiB, 16B-aligned rows
  __shared__ int xin[16][128];           // 8 KiB
  __shared__ int len1[16];

  const int bid = blockIdx.x;
  const int g = bid & 15;        // group id
  const int c = bid >> 4;        // col-block
  const int row0 = g * 16, col0 = c * 64;
  const int tid = threadIdx.x;
  const int w = tid >> 6, lane = tid & 63, lr = lane & 15, lk = lane >> 4;
  int* gflags = flags + g * SS;

  // ---- stage W slice into LDS (one-time, 256 KB f32 -> 128 KB f16)
  for (int idx = tid; idx < 64 * 256; idx += 256) {
    const int col = idx >> 8;            // 0..63
    const int kq  = (idx & 255) * 4;     // 0..1020 step 4
    const f32x4 v = *(const f32x4*)(W_hh + (size_t)(col0 + col) * HH + kq);
    f16x4 hv;
    hv[0] = (_Float16)v.x; hv[1] = (_Float16)v.y;
    hv[2] = (_Float16)v.z; hv[3] = (_Float16)v.w;
    *(f16x4*)(&wlds[col * WPAD + kq]) = hv;
  }
  for (int i = tid; i < 16 * SS; i += 256) {
    const int r_ = i >> 7, s_ = i & 127;
    xin[r_][s_] = x_in[(row0 + r_) * SS + s_];
  }
  if (tid < 16) len1[tid] = x_len[row0 + tid] - 1;
  __syncthreads();

  int gmax = 0;
#pragma unroll
  for (int r16 = 0; r16 < 16; ++r16) gmax = max(gmax, len1[r16]);

  const int arow = row0 + lr;
  const int r = tid >> 4, cc0 = (tid & 15) * 4;
  const int grow = row0 + r;
  // per-lane LDS base for W fragments: row lr (within nt-tile), this wave's k-quarter
  const int wbase = lr * WPAD + w * 256 + lk * 8;

  // ---- t = 0: h0 == 0, so h1 = tanh(pre_0). No loads, no MFMA.
  {
    const int vv = xin[r][0];
    const f32x4 pre4 = *(const f32x4*)(ep + vv * HH + col0 + cc0);
    float th[4];
    th[0] = tanh_fast(pre4.x); th[1] = tanh_fast(pre4.y);
    th[2] = tanh_fast(pre4.z); th[3] = tanh_fast(pre4.w);

    if (len1[r] == 0) {
      f32x4 o; o.x = th[0]; o.y = th[1]; o.z = th[2]; o.w = th[3];
      *(f32x4*)(lastb + (size_t)grow * HH + col0 + cc0) = o;
    }
    if (gmax >= 1) {
      f16x4 h4, l4;
#pragma unroll
      for (int i = 0; i < 4; ++i) {
        const _Float16 hh = (_Float16)th[i];
        h4[i] = hh;
        l4[i] = (_Float16)((th[i] - (float)hh) * 4096.0f);
      }
      st_cp8(hbuf + ((size_t)(1 * 2 + 0) * BB + grow) * HH + col0 + cc0, h4);
      st_cp8(hbuf + ((size_t)(1 * 2 + 1) * BB + grow) * HH + col0 + cc0, l4);
      __syncthreads();                     // drain all waves' sc1 stores
      if (tid == 0) {
        __hip_atomic_fetch_add(&gflags[0], 1, __ATOMIC_RELAXED, __HIP_MEMORY_SCOPE_AGENT);
        while (__hip_atomic_load(&gflags[0], __ATOMIC_RELAXED,
                                 __HIP_MEMORY_SCOPE_AGENT) < 16) {
          __builtin_amdgcn_s_sleep(1);
        }
      }
      __syncthreads();
      asm volatile("" ::: "memory");
    }
  }

  for (int t = 1; t <= gmax; ++t) {
    const int bufR = t & 1;
    const _Float16* hr_hi = hbuf + ((size_t)(bufR * 2 + 0) * BB + arow) * HH;
    const _Float16* hr_lo = hbuf + ((size_t)(bufR * 2 + 1) * BB + arow) * HH;

    // this step's ep gather: issue early, independent of h
    const int vv = xin[r][t];
    const f32x4 pre4 = *(const f32x4*)(ep + vv * HH + col0 + cc0);

    // ---- phase 1: issue all h loads (sc1); ds_reads below hide under them
    f16x8 ahi[8], alo[8];
#pragma unroll
    for (int ki = 0; ki < 8; ++ki) {
      const int k = w * 256 + ki * 32 + lk * 8;
      ahi[ki] = ld_cp16(hr_hi + k);
      alo[ki] = ld_cp16(hr_lo + k);
    }

    // ---- phase 2: MFMA with W fragments streamed from LDS
    f32x4 acch[4] = {};
    f32x4 accl[4] = {};
#pragma unroll
    for (int ki = 0; ki < 8; ++ki) {
#pragma unroll
      for (int nt = 0; nt < 4; ++nt) {
        const f16x8 wf = *(const f16x8*)(&wlds[wbase + nt * (16 * WPAD) + ki * 32]);
        acch[nt] = __builtin_amdgcn_mfma_f32_16x16x32_f16(ahi[ki], wf, acch[nt], 0, 0, 0);
        accl[nt] = __builtin_amdgcn_mfma_f32_16x16x32_f16(alo[ki], wf, accl[nt], 0, 0, 0);
      }
    }
#pragma unroll
    for (int nt = 0; nt < 4; ++nt)
#pragma unroll
      for (int j = 0; j < 4; ++j)
        red[w][lk * 4 + j][nt * 16 + lr] = acch[nt][j] + accl[nt][j] * (1.0f / 4096.0f);
    __syncthreads();

    // ---- phase 3: vectorized cross-wave reduce + tanh
    const f32x4 s0 = *(const f32x4*)&red[0][r][cc0];
    const f32x4 s1 = *(const f32x4*)&red[1][r][cc0];
    const f32x4 s2 = *(const f32x4*)&red[2][r][cc0];
    const f32x4 s3 = *(const f32x4*)&red[3][r][cc0];
    const f32x4 sv = (s0 + s1) + (s2 + s3);

    float th[4];
    th[0] = tanh_fast(sv.x + pre4.x);
    th[1] = tanh_fast(sv.y + pre4.y);
    th[2] = tanh_fast(sv.z + pre4.z);
    th[3] = tanh_fast(sv.w + pre4.w);

    if (len1[r] == t) {
      f32x4 o; o.x = th[0]; o.y = th[1]; o.z = th[2]; o.w = th[3];
      *(f32x4*)(lastb + (size_t)grow * HH + col0 + cc0) = o;
    }

    if (t < gmax) {
      const int bufW = bufR ^ 1;
      f16x4 h4, l4;
#pragma unroll
      for (int i = 0; i < 4; ++i) {
        const _Float16 hh = (_Float16)th[i];
        h4[i] = hh;
        l4[i] = (_Float16)((th[i] - (float)hh) * 4096.0f);
      }
      st_cp8(hbuf + ((size_t)(bufW * 2 + 0) * BB + grow) * HH + col0 + cc0, h4);
      st_cp8(hbuf + ((size_t)(bufW * 2 + 1) * BB + grow) * HH + col0 + cc0, l4);

      __syncthreads();                     // drain all waves' sc1 stores
      if (tid == 0) {
        __hip_atomic_fetch_add(&gflags[t], 1, __ATOMIC_RELAXED, __HIP_MEMORY_SCOPE_AGENT);
        while (__hip_atomic_load(&gflags[t], __ATOMIC_RELAXED,
                                 __HIP_MEMORY_SCOPE_AGENT) < 16) {
          __builtin_amdgcn_s_sleep(1);
        }
      }
      __syncthreads();
      asm volatile("" ::: "memory");       // no hoisting of next-step loads above the barrier
    }
  }
}

// ---------------- K3: z = relu(last @ W1^T + b1).
__global__ __launch_bounds__(256) void k_mlp1(const float* __restrict__ lastb,
                                              const float* __restrict__ W1,
                                              const float* __restrict__ b1,
                                              float* __restrict__ z) {
  __shared__ float red[4][16][66];
  const int bid = blockIdx.x;
  const int row0 = (bid & 15) * 16, col0 = (bid >> 4) * 64;
  const int tid = threadIdx.x;
  const int w = tid >> 6, lane = tid & 63, lr = lane & 15, lk = lane >> 4;
  const int arow = row0 + lr;

  f32x4 acch[4] = {};
  f32x4 accl[4] = {};
#pragma unroll
  for (int ki = 0; ki < 8; ++ki) {
    const int k = w * 256 + ki * 32 + lk * 8;
    const f32x4* pa = (const f32x4*)(lastb + (size_t)arow * HH + k);
    f32x4 a0 = pa[0], a1 = pa[1];
    f16x8 ahi, alo;
#pragma unroll
    for (int i = 0; i < 4; ++i) {
      float v0 = (i == 0) ? a0.x : (i == 1) ? a0.y : (i == 2) ? a0.z : a0.w;
      float v1 = (i == 0) ? a1.x : (i == 1) ? a1.y : (i == 2) ? a1.z : a1.w;
      _Float16 h0 = (_Float16)v0, h1 = (_Float16)v1;
      ahi[i] = h0; ahi[i + 4] = h1;
      alo[i] = (_Float16)((v0 - (float)h0) * 4096.0f);
      alo[i + 4] = (_Float16)((v1 - (float)h1) * 4096.0f);
    }
#pragma unroll
    for (int nt = 0; nt < 4; ++nt) {
      const int colw = col0 + nt * 16 + lr;
      const f32x4* pb = (const f32x4*)(W1 + (size_t)colw * HH + k);
      f16x8 bf = cvt8(pb[0], pb[1]);
      acch[nt] = __builtin_amdgcn_mfma_f32_16x16x32_f16(ahi, bf, acch[nt], 0, 0, 0);
      accl[nt] = __builtin_amdgcn_mfma_f32_16x16x32_f16(alo, bf, accl[nt], 0, 0, 0);
    }
  }
#pragma unroll
  for (int nt = 0; nt < 4; ++nt)
#pragma unroll
    for (int j = 0; j < 4; ++j)
      red[w][lk * 4 + j][nt * 16 + lr] = acch[nt][j] + accl[nt][j] * (1.0f / 4096.0f);
  __syncthreads();

  const int r = tid >> 4, cc0 = (tid & 15) * 4;
  const int grow = row0 + r;
#pragma unroll
  for (int i = 0; i < 4; ++i) {
    const int col = col0 + cc0 + i;
    float s = red[0][r][cc0 + i] + red[1][r][cc0 + i] +
              red[2][r][cc0 + i] + red[3][r][cc0 + i] + b1[col];
    z[(size_t)grow * HH + col] = fmaxf(s, 0.0f);
  }
}

// ---------------- K4: y = z @ W2^T + b2. One block per batch row, fp32 wave reduce.
__global__ __launch_bounds__(256) void k_mlp2(const float* __restrict__ z,
                                              const float* __restrict__ W2,
                                              const float* __restrict__ b2,
                                              float* __restrict__ out) {
  __shared__ float redy[4][CC];
  const int b = blockIdx.x;
  const int tid = threadIdx.x;
  const int w = tid >> 6, lane = tid & 63;
  const int k = w * 256 + lane * 4;

  const f32x4 z4 = *(const f32x4*)(z + (size_t)b * HH + k);
  float part[CC];
#pragma unroll
  for (int c = 0; c < CC; ++c) {
    const f32x4 w4 = *(const f32x4*)(W2 + (size_t)c * HH + k);
    part[c] = z4.x * w4.x + z4.y * w4.y + z4.z * w4.z + z4.w * w4.w;
  }
#pragma unroll
  for (int c = 0; c < CC; ++c) {
    float v = part[c];
    for (int off = 32; off; off >>= 1) v += __shfl_down(v, off, 64);
    if (lane == 0) redy[w][c] = v;
  }
  __syncthreads();
  if (tid < CC)
    out[b * CC + tid] = redy[0][tid] + redy[1][tid] + redy[2][tid] + redy[3][tid] + b2[tid];
}

extern "C" void kernel_launch(void* const* d_in, const int* in_sizes, int n_in,
                              void* d_out, int out_size, void* d_ws, size_t ws_size,
                              hipStream_t stream) {
  const int*   x_in  = (const int*)d_in[0];
  const int*   x_len = (const int*)d_in[1];
  const float* emb   = (const float*)d_in[2];
  const float* W_ih  = (const float*)d_in[3];
  const float* b_ih  = (const float*)d_in[4];
  const float* W_hh  = (const float*)d_in[5];
  const float* b_hh  = (const float*)d_in[6];
  const float* W1    = (const float*)d_in[7];
  const float* b1    = (const float*)d_in[8];
  const float* W2    = (const float*)d_in[9];
  const float* b2    = (const float*)d_in[10];

  char* ws = (char*)d_ws;
  _Float16* hbuf = (_Float16*)(ws + HBUF_OFF);
  int* flags     = (int*)(ws + FLAGS_OFF);
  float* ep      = (float*)(ws + EP_OFF);
  float* lastb   = (float*)(ws + LAST_OFF);
  float* z       = (float*)(ws + Z_OFF);

  // step-arrival flags = 0 (hbuf is written before read; no memset needed)
  (void)hipMemsetAsync(flags, 0, 16 * SS * 4, stream);

  hipLaunchKernelGGL(k_embproj, dim3(128), dim3(256), 0, stream, emb, W_ih, b_ih, b_hh, ep);
  hipLaunchKernelGGL(k_rnn,    dim3(256), dim3(256), 0, stream, W_hh, x_in, x_len, ep, hbuf, flags, lastb);
  hipLaunchKernelGGL(k_mlp1,   dim3(256), dim3(256), 0, stream, lastb, W1, b1, z);
  hipLaunchKernelGGL(k_mlp2,   dim3(256), dim3(256), 0, stream, z, W2, b2, (float*)d_out);
}